// Round 8
// baseline (607.743 us; speedup 1.0000x reference)
//
#include <hip/hip_runtime.h>

// Problem constants (match reference setup_inputs)
#define NN 50000
#define EE 800000
#define DD 256
#define LL 3
#define GG 512
#define MPAD 50048   // 1564 * 32, GEMM row-tile padding
#define RPC  12512   // rows per pipeline chunk (MPAD/4), mult of 32 and 4
#define GB   (RPC / 4)    // 3128 gather blocks per chunk
#define MB   (RPC / 32)   // 391 mlp blocks per chunk

typedef __attribute__((ext_vector_type(4))) _Float16 half4;
typedef __attribute__((ext_vector_type(8))) _Float16 half8;
typedef __attribute__((ext_vector_type(16))) float floatx16;

// ---------------------------------------------------------------------------
// Fused prep kernel (independent work, split by blockIdx range):
//   [0, 12500)        : x fp32 -> fp16 convert (row-major h)
//   [12500, 12692)    : weight pack (192 blocks)
//   [12692, 15817)    : degree histogram (3125 blocks)
// ---------------------------------------------------------------------------
#define CONV_B 12500
#define WPK_B  192
#define HIST_B 3125

__global__ void k_prep(const float* __restrict__ x, _Float16* __restrict__ h16,
                       const float* __restrict__ Ws1, const float* __restrict__ Ws2,
                       _Float16* __restrict__ Wp,
                       const int* __restrict__ dst, int* __restrict__ deg) {
    int b = blockIdx.x;
    if (b < CONV_B) {
        int i = b * 256 + threadIdx.x;  // float4 groups, NN*DD/4 = 3.2M
        if (i >= NN * DD / 4) return;
        float4 v = ((const float4*)x)[i];
        half4 o;
        o.x = (_Float16)v.x; o.y = (_Float16)v.y; o.z = (_Float16)v.z; o.w = (_Float16)v.w;
        ((half4*)h16)[i] = o;
    } else if (b < CONV_B + WPK_B) {
        // Pre-pack W (fp32 [256,256], k-major) into fp16 MFMA B-fragments for
        // mfma_f32_32x32x16_f16. Fragment (ks,nb): lane l holds
        // B[ks*16 + (l>>5)*8 + j][nb*32 + (l&31)], j=0..7.
        int tid  = (b - CONV_B) * 256 + threadIdx.x;  // 6*16*8*64 = 49152
        int lane = tid & 63;
        int nb   = (tid >> 6) & 7;
        int ks   = (tid >> 9) & 15;
        int w    = tid >> 13;
        if (w >= 6) return;
        int l = w >> 1, s = w & 1;
        const float* W = (s == 0 ? Ws1 : Ws2) + (size_t)l * DD * DD;
        int kbase = ks * 16 + (lane >> 5) * 8;
        int n     = nb * 32 + (lane & 31);
        half8 hi;
#pragma unroll
        for (int j = 0; j < 8; ++j) hi[j] = (_Float16)W[(size_t)(kbase + j) * DD + n];
        ((half8*)Wp)[(((size_t)w * 16 + ks) * 8 + nb) * 64 + lane] = hi;
    } else {
        int i = (b - CONV_B - WPK_B) * 256 + threadIdx.x;
        if (i < EE) atomicAdd(&deg[dst[i]], 1);
    }
}

// ---------------------------------------------------------------------------
// CSR build: 3-kernel parallel scan -> scatter (histogram is in k_prep)
// ---------------------------------------------------------------------------
__global__ void k_scan1(const int* __restrict__ deg, int* __restrict__ rp,
                        int* __restrict__ bsum, int n) {
    __shared__ int s[1024];
    int t = threadIdx.x;
    int i = blockIdx.x * 1024 + t;
    int v = (i < n) ? deg[i] : 0;
    s[t] = v;
    __syncthreads();
    for (int off = 1; off < 1024; off <<= 1) {
        int tmp = (t >= off) ? s[t - off] : 0;
        __syncthreads();
        s[t] += tmp;
        __syncthreads();
    }
    if (i < n) rp[i] = s[t] - v;          // local exclusive
    if (t == 1023) bsum[blockIdx.x] = s[1023];
}

__global__ void k_scan2(int* __restrict__ bsum, int nb, int* __restrict__ total_out) {
    int lane = threadIdx.x & 63;
    int v = (lane < nb) ? bsum[lane] : 0;
    int orig = v;
    for (int off = 1; off < 64; off <<= 1) {
        int u = __shfl_up(v, off);
        if (lane >= off) v += u;
    }
    if (lane < nb) bsum[lane] = v - orig;  // exclusive block offsets
    if (lane == 63) *total_out = v;        // grand total -> row_ptr[N]
}

__global__ void k_scan3(int* __restrict__ rp, const int* __restrict__ bsum,
                        int* __restrict__ cursor, int n) {
    int i = blockIdx.x * 1024 + threadIdx.x;
    if (i < n) {
        int v = rp[i] + bsum[blockIdx.x];
        rp[i] = v;
        cursor[i] = v;
    }
}

__global__ void k_scatter(const int* __restrict__ src, const int* __restrict__ dst,
                          int* __restrict__ cursor, int* __restrict__ csr_src, int e) {
    int i = blockIdx.x * blockDim.x + threadIdx.x;
    if (i < e) {
        int d = dst[i];
        int pos = atomicAdd(&cursor[d], 1);
        csr_src[pos] = src[i];
    }
}

// ---------------------------------------------------------------------------
// Gather body (round-3/7 form): agg[n] = h[n] + sum_{j->n} h[j].
// One wave per node, 4 nodes per 256-thread block; lanes 0-31 even edges,
// lanes 32-63 odd; 8 half8 loads in flight; CSR segment staged in LDS;
// cross-half fold via shfl_xor(32).
// ---------------------------------------------------------------------------
__device__ __forceinline__ void gather_body(
        const _Float16* __restrict__ h,
        const int* __restrict__ row_ptr,
        const int* __restrict__ csr_src,
        _Float16* agg, int n0, int* eidx, int* rp_s) {
    int t = threadIdx.x, lane = t & 63, w = t >> 6;
    if (t < 5) {
        int nn = n0 + t;
        if (nn > NN) nn = NN;
        rp_s[t] = row_ptr[nn];
    }
    __syncthreads();
    int beg0 = rp_s[0];
    int cnt  = rp_s[4] - beg0;
    for (int i = t; i < cnt && i < 1024; i += 256) eidx[i] = csr_src[beg0 + i];
    __syncthreads();

    int n = n0 + w;
    if (n >= NN) return;
    int beg = rp_s[w] - beg0, end = rp_s[w + 1] - beg0;
    int hf = lane >> 5;   // 0: own row + even edges; 1: odd edges
    int cl = lane & 31;   // column group: cols [cl*8, cl*8+8)
    const half8* hp = (const half8*)h;  // row n = hp[n*32 + cl]

    half8 acc;
#pragma unroll
    for (int i = 0; i < 8; ++i) acc[i] = (_Float16)0;
    if (hf == 0) acc = hp[(size_t)n * 32 + cl];

    if (cnt <= 1024) {
        int k = beg;
        for (; k + 16 <= end; k += 16) {
            half8 v[8];
#pragma unroll
            for (int u = 0; u < 8; ++u) {
                int s = eidx[k + 2 * u + hf];
                v[u] = hp[(size_t)s * 32 + cl];
            }
#pragma unroll
            for (int u = 0; u < 8; ++u) acc += v[u];
        }
        if (k < end) {  // tail < 16 edges: predicated, all loads in flight
#pragma unroll
            for (int u = 0; u < 8; ++u) {
                int e = k + 2 * u + hf;
                half8 v;
#pragma unroll
                for (int i = 0; i < 8; ++i) v[i] = (_Float16)0;
                if (e < end) v = hp[(size_t)eidx[e] * 32 + cl];
                acc += v;
            }
        }
    } else {
        // rare fallback: indices from global
        int k = beg;
        for (; k + 16 <= end; k += 16) {
            half8 v[8];
#pragma unroll
            for (int u = 0; u < 8; ++u) {
                int s = csr_src[beg0 + k + 2 * u + hf];
                v[u] = hp[(size_t)s * 32 + cl];
            }
#pragma unroll
            for (int u = 0; u < 8; ++u) acc += v[u];
        }
        if (k < end) {
#pragma unroll
            for (int u = 0; u < 8; ++u) {
                int e = k + 2 * u + hf;
                half8 v;
#pragma unroll
                for (int i = 0; i < 8; ++i) v[i] = (_Float16)0;
                if (e < end) v = hp[(size_t)csr_src[beg0 + e] * 32 + cl];
                acc += v;
            }
        }
    }

    // fold odd-half into even-half (16 B = int4 via 4 shfl_xor)
    int4 ai = *(int4*)&acc;
    int4 bi;
    bi.x = __shfl_xor(ai.x, 32);
    bi.y = __shfl_xor(ai.y, 32);
    bi.z = __shfl_xor(ai.z, 32);
    bi.w = __shfl_xor(ai.w, 32);
    acc += *(half8*)&bi;
    if (hf == 0) ((half8*)(agg + (size_t)n * DD))[cl] = acc;
}

// ---------------------------------------------------------------------------
// MLP body (round-7 32-row tile): h_out = relu(relu(A@W1+b1)@W2+b2).
// Block: 4 waves over a 32-row x 256-col tile; wave w owns 32x64 (2 n-tiles
// of mfma_f32_32x32x16_f16). GEMM1 A direct from global; t through swizzled
// fp16 LDS; Hout regular store (nullptr on last layer); Fout nontemporal;
// per-graph pool partials atomically into Gout.
// ---------------------------------------------------------------------------
__device__ __forceinline__ void mlp_body(
        const _Float16* __restrict__ A,
        const int* __restrict__ batch,
        const _Float16* __restrict__ Wp1, const float* __restrict__ b1,
        const _Float16* __restrict__ Wp2, const float* __restrict__ b2,
        _Float16* Hout, float* __restrict__ Fout, float* __restrict__ Gout,
        int r0, _Float16* t_lds, int* batch_s) {
    int t    = threadIdx.x;
    int lane = t & 63;
    int w    = t >> 6;                     // wave = n-quadrant [w*64, w*64+64)

    if (t < 32) {
        int r = r0 + t;
        batch_s[t] = (r < NN) ? batch[r] : 0x7fffffff;
    }

    // ---- GEMM1: acc = A @ W1 (A fragments direct from global) ----
    int arow = r0 + (lane & 31);
    const half8* baseA = (const half8*)(A + (size_t)arow * DD) + (lane >> 5);
    const half8* B1    = (const half8*)Wp1;

    floatx16 acc[2];
#pragma unroll
    for (int nt = 0; nt < 2; ++nt)
#pragma unroll
        for (int i = 0; i < 16; ++i) acc[nt][i] = 0.0f;

#pragma unroll 4
    for (int ks = 0; ks < 16; ++ks) {
        half8 a = baseA[ks * 2];
#pragma unroll
        for (int nt = 0; nt < 2; ++nt) {
            half8 b = B1[(size_t)(ks * 8 + w * 2 + nt) * 64 + lane];
            acc[nt] = __builtin_amdgcn_mfma_f32_32x32x16_f16(a, b, acc[nt], 0, 0, 0);
        }
    }

    // ---- epilogue 1: t = relu(acc + b1) -> LDS (fp16, swizzled) ----
#pragma unroll
    for (int nt = 0; nt < 2; ++nt) {
        int c  = w * 64 + nt * 32 + (lane & 31);
        float bv = b1[c];
#pragma unroll
        for (int reg = 0; reg < 16; ++reg) {
            int lr = (reg & 3) + 8 * (reg >> 2) + 4 * (lane >> 5);  // 0..31
            float v = fmaxf(acc[nt][reg] + bv, 0.0f);
            t_lds[lr * 256 + ((((c >> 3) ^ (lr & 7)) << 3) | (c & 7))] = (_Float16)v;
        }
    }
    __syncthreads();

    // ---- GEMM2: acc2 = t @ W2 (A fragments from swizzled LDS) ----
    const half8* B2 = (const half8*)Wp2;
    int r = lane & 31;
    floatx16 acc2[2];
#pragma unroll
    for (int nt = 0; nt < 2; ++nt)
#pragma unroll
        for (int i = 0; i < 16; ++i) acc2[nt][i] = 0.0f;

#pragma unroll 4
    for (int ks = 0; ks < 16; ++ks) {
        int kblk = ks * 2 + (lane >> 5);
        half8 a = *(const half8*)&t_lds[r * 256 + ((kblk ^ (r & 7)) << 3)];
#pragma unroll
        for (int nt = 0; nt < 2; ++nt) {
            half8 b = B2[(size_t)(ks * 8 + w * 2 + nt) * 64 + lane];
            acc2[nt] = __builtin_amdgcn_mfma_f32_32x32x16_f16(a, b, acc2[nt], 0, 0, 0);
        }
    }

    // ---- epilogue 2: h = relu(acc2 + b2) -> fp16 Hout + fp32 node_embed ----
    const int rbase = 4 * (lane >> 5);
#pragma unroll
    for (int nt = 0; nt < 2; ++nt) {
        int col = w * 64 + nt * 32 + (lane & 31);
        float bv = b2[col];
#pragma unroll
        for (int reg = 0; reg < 16; ++reg) {
            int rowid = rbase + (reg & 3) + 8 * (reg >> 2);   // 0..31
            int row = r0 + rowid;
            if (row < NN) {
                float v = fmaxf(acc2[nt][reg] + bv, 0.0f);
                if (Hout) Hout[(size_t)row * DD + col] = (_Float16)v;
                __builtin_nontemporal_store(v, &Fout[(size_t)row * 768 + col]);
            }
        }
    }

    // ---- pool accumulate: per-graph column sums (batch sorted; the tile's
    //      32 rows span 1-2 graphs). Cross-half merge by shfl_xor(32),
    //      then one atomicAdd per (graph, col) partial.
    int lastid = NN - 1 - r0;
    if (lastid >= 0) {
        if (lastid > 31) lastid = 31;
        int g0 = batch_s[0];
        int g1 = batch_s[lastid];
        for (int g = g0; g <= g1; ++g) {
#pragma unroll
            for (int nt = 0; nt < 2; ++nt) {
                int col = w * 64 + nt * 32 + (lane & 31);
                float bv = b2[col];
                float s = 0.0f;
#pragma unroll
                for (int reg = 0; reg < 16; ++reg) {
                    int rowid = rbase + (reg & 3) + 8 * (reg >> 2);
                    if (batch_s[rowid] == g)
                        s += fmaxf(acc2[nt][reg] + bv, 0.0f);
                }
                s += __shfl_xor(s, 32);
                if (lane < 32)
                    atomicAdd(&Gout[(size_t)g * 768 + col], s);
            }
        }
    }
}

// ---------------------------------------------------------------------------
// Standalone kernels (pipeline head/tail) + combined pipeline kernel.
// k_gm: blocks [0, mlp_blocks) run mlp on chunk c (rows mlp_rbeg..+RPC);
//       blocks [mlp_blocks, ...) run gather on chunk c+1. The two roles are
//       fully independent (gather reads hin/writes agg[c+1]; mlp reads
//       agg[c]/writes hout+Fout+Gout) -- no intra-kernel ordering, the
//       overlap hides gather's memory latency under mlp's MFMA waves.
// mlp blocks FIRST so they start immediately (391 vs 3128 gather blocks).
// ---------------------------------------------------------------------------
__global__ __launch_bounds__(256) void k_gather(
        const _Float16* __restrict__ h, const int* __restrict__ row_ptr,
        const int* __restrict__ csr_src, _Float16* agg, int nbeg) {
    __shared__ int eidx[1024];
    __shared__ int rp_s[5];
    gather_body(h, row_ptr, csr_src, agg, nbeg + blockIdx.x * 4, eidx, rp_s);
}

__global__ __launch_bounds__(256) void k_mlp(
        const _Float16* __restrict__ A, const int* __restrict__ batch,
        const _Float16* __restrict__ Wp1, const float* __restrict__ b1,
        const _Float16* __restrict__ Wp2, const float* __restrict__ b2,
        _Float16* Hout, float* __restrict__ Fout, float* __restrict__ Gout,
        int rbeg) {
    __shared__ _Float16 t_lds[32 * 256];   // 16 KB
    __shared__ int batch_s[32];
    mlp_body(A, batch, Wp1, b1, Wp2, b2, Hout, Fout, Gout,
             rbeg + blockIdx.x * 32, t_lds, batch_s);
}

__global__ __launch_bounds__(256) void k_gm(
        const _Float16* __restrict__ hin, const int* __restrict__ row_ptr,
        const int* __restrict__ csr_src, _Float16* agg,
        const int* __restrict__ batch,
        const _Float16* __restrict__ Wp1, const float* __restrict__ b1,
        const _Float16* __restrict__ Wp2, const float* __restrict__ b2,
        _Float16* Hout, float* __restrict__ Fout, float* __restrict__ Gout,
        int mlp_blocks, int mlp_rbeg, int gather_nbeg) {
    __shared__ _Float16 t_lds[32 * 256];   // 16 KB (mlp)
    __shared__ int batch_s[32];
    __shared__ int eidx[1024];             // 4 KB (gather)
    __shared__ int rp_s[5];
    if ((int)blockIdx.x < mlp_blocks) {
        mlp_body(agg, batch, Wp1, b1, Wp2, b2, Hout, Fout, Gout,
                 mlp_rbeg + blockIdx.x * 32, t_lds, batch_s);
    } else {
        gather_body(hin, row_ptr, csr_src, agg,
                    gather_nbeg + (blockIdx.x - mlp_blocks) * 4, eidx, rp_s);
    }
}

// ---------------------------------------------------------------------------
// Finalize pool: graph_embed = gsum / count. One block per graph.
// ---------------------------------------------------------------------------
__global__ void k_pool_final(const float* __restrict__ gsum,
                             const int* __restrict__ batch,
                             float* __restrict__ graph_embed) {
    int g = blockIdx.x;
    int t = threadIdx.x;  // 0..191
    int start, end;
    { int l = 0, h = NN; while (l < h) { int m = (l + h) >> 1; if (batch[m] < g) l = m + 1; else h = m; } start = l; }
    { int l = 0, h = NN; while (l < h) { int m = (l + h) >> 1; if (batch[m] < g + 1) l = m + 1; else h = m; } end = l; }
    int cnt = end - start;
    float inv = 1.0f / (float)(cnt > 0 ? cnt : 1);
    float4 v = ((const float4*)(gsum + (size_t)g * 768))[t];
    float4 o; o.x = v.x * inv; o.y = v.y * inv; o.z = v.z * inv; o.w = v.w * inv;
    ((float4*)(graph_embed + (size_t)g * 768))[t] = o;
}

// ---------------------------------------------------------------------------
extern "C" void kernel_launch(void* const* d_in, const int* in_sizes, int n_in,
                              void* d_out, int out_size, void* d_ws, size_t ws_size,
                              hipStream_t stream) {
    const float* x     = (const float*)d_in[0];  // [N, 256]
    const int*   ei    = (const int*)d_in[1];    // [2, E]
    const int*   batch = (const int*)d_in[2];    // [N] (sorted)
    const float* Ws1   = (const float*)d_in[3];  // [L, 256, 256]
    const float* bs1   = (const float*)d_in[4];  // [L, 256]
    const float* Ws2   = (const float*)d_in[5];  // [L, 256, 256]
    const float* bs2   = (const float*)d_in[6];  // [L, 256]

    float* out         = (float*)d_out;
    float* graph_embed = out;                     // [G, 768]
    float* node_embed  = out + (size_t)GG * 768;  // [N, 768]

    // Workspace (re-poisoned before every call; fully rebuilt here).
    // h double-buffered: pipelined layer reads h(l-1) while writing h(l).
    _Float16* h16   = (_Float16*)d_ws;                  // [MPAD, 256]
    _Float16* h_alt = h16 + (size_t)MPAD * DD;          // [MPAD, 256]
    _Float16* agg16 = h_alt + (size_t)MPAD * DD;        // [MPAD, 256]
    _Float16* Wp    = agg16 + (size_t)MPAD * DD;        // 6 * 65536 halfs
    float* gsum     = (float*)(Wp + (size_t)6 * 65536); // [G, 768]   (zeroed)
    int* cursor     = (int*)(gsum + (size_t)GG * 768);  // [N] (also deg, zeroed)
    int* bsum       = cursor + NN;                      // [64]       (zeroed)
    int* csr_src    = bsum + 64;                        // [E]
    int* row_ptr    = csr_src + EE;                     // [N+1]

    const int* src = ei;       // edge_index[0]
    const int* dst = ei + EE;  // edge_index[1]

    const int NB = (NN + 1023) / 1024;  // 49 scan blocks

    // Zero gsum + cursor + bsum in one contiguous memset (before k_prep hist!)
    hipMemsetAsync(gsum, 0, (size_t)GG * 768 * 4 + (size_t)NN * 4 + 64 * 4, stream);

    // convert + wpack + hist in one launch
    k_prep<<<CONV_B + WPK_B + HIST_B, 256, 0, stream>>>(x, h16, Ws1, Ws2, Wp, dst, cursor);

    // Finish CSR (dst -> list of src)
    k_scan1<<<NB, 1024, 0, stream>>>(cursor, row_ptr, bsum, NN);
    k_scan2<<<1, 64, 0, stream>>>(bsum, NB, row_ptr + NN);
    k_scan3<<<NB, 1024, 0, stream>>>(row_ptr, bsum, cursor, NN);
    k_scatter<<<(EE + 255) / 256, 256, 0, stream>>>(src, dst, cursor, csr_src, EE);

    // Pipelined layers: gather(c0) | [mlp(c)||gather(c+1)] x3 | mlp(c3)
    for (int l = 0; l < LL; ++l) {
        const _Float16* hin  = (l & 1) ? h_alt : h16;
        _Float16*       hout = (l == LL - 1) ? nullptr : ((l & 1) ? h16 : h_alt);
        const _Float16* W1 = Wp + (size_t)(2 * l + 0) * 65536;
        const _Float16* W2 = Wp + (size_t)(2 * l + 1) * 65536;
        const float* bb1 = bs1 + (size_t)l * DD;
        const float* bb2 = bs2 + (size_t)l * DD;
        float* F  = node_embed + (size_t)l * DD;
        float* Gp = gsum + (size_t)l * DD;

        k_gather<<<GB, 256, 0, stream>>>(hin, row_ptr, csr_src, agg16, 0);
        for (int c = 0; c < 3; ++c)
            k_gm<<<MB + GB, 256, 0, stream>>>(
                hin, row_ptr, csr_src, agg16, batch,
                W1, bb1, W2, bb2, hout, F, Gp,
                MB, c * RPC, (c + 1) * RPC);
        k_mlp<<<MB, 256, 0, stream>>>(agg16, batch, W1, bb1, W2, bb2,
                                      hout, F, Gp, 3 * RPC);
    }

    k_pool_final<<<GG, 192, 0, stream>>>(gsum, batch, graph_embed);
}